// Round 11
// baseline (977.567 us; speedup 1.0000x reference)
//
#include <hip/hip_runtime.h>
#include <cstdint>
#include <cstddef>

#pragma clang diagnostic ignored "-Waddress-space-conversion"

constexpr int T   = 16;
constexpr int N   = 10000;
constexpr int M   = 2048;
constexpr int F   = 256;
constexpr int H   = 256;
constexpr int G4  = 1024;
constexpr int NP  = 10112;   // N padded to 128
constexpr int NP2 = 10240;   // N padded to 256 (chain: 40 blocks x 2 m-tiles)

typedef _Float16 f16;
using half8  = __attribute__((ext_vector_type(8))) f16;
using half4  = __attribute__((ext_vector_type(4))) f16;
using f32x4  = __attribute__((ext_vector_type(4))) float;

typedef __attribute__((address_space(1))) const void gas_t;
typedef __attribute__((address_space(3))) void las_t;

__device__ __forceinline__ void gl_lds16(const f16* g, f16* l) {
    __builtin_amdgcn_global_load_lds((gas_t*)g, (las_t*)l, 16, 0, 0);
}

__device__ __forceinline__ float fast_tanh(float x) {
    const float ax = fabsf(x);
    const float e  = __expf(-2.f * ax);
    const float t  = (1.f - e) / (1.f + e);
    return copysignf(t, x);
}

// ---------------------------------------------------------------------------
// Generic MFMA GEMM (round-7 structure, unchanged).
// NOTE (r8 lesson): no global stores inside the staged K-loop (vmcnt drain).
// NOTE (r10 lesson): grid.sync() persistent chain = 116 us/step; dead end.
// ---------------------------------------------------------------------------
template<bool AF32, bool RELU, int OMODE>
__global__ __launch_bounds__(256, 2)
void gemm16(const void* __restrict__ Ag, long long sA,
            const f16*  __restrict__ Bg, long long sB,
            void*       __restrict__ Cg, long long sC,
            int Kk, int Nn, int Mvalid, int ldct)
{
    __shared__ f16 Als[2][128 * 32];
    __shared__ f16 Bls[2][128 * 32];

    const int tid  = threadIdx.x;
    const int lane = tid & 63;
    const int w    = tid >> 6;
    const int wm   = w >> 1, wn = w & 1;
    const int m0   = blockIdx.y * 128, n0 = blockIdx.x * 128;
    const int z    = blockIdx.z;

    const f16* Bt = Bg + (size_t)z * sB;
    const int srow = lane >> 2;
    const int scol = (lane & 3) * 8;

    f32x4 acc[4][4] = {};

    auto stage = [&](int buf, int kt) {
        const int k0 = kt * 32;
        #pragma unroll
        for (int c = 0; c < 2; ++c) {
            const int brow = w * 32 + c * 16;
            gl_lds16(Bt + (size_t)(n0 + brow + srow) * Kk + k0 + scol,
                     &Bls[buf][brow * 32]);
        }
        if constexpr (AF32) {
            const float* Af = (const float*)Ag + (size_t)z * sA;
            #pragma unroll
            for (int p = 0; p < 4; ++p) {
                const int flat = p * 1024 + tid * 4;
                const int r = flat >> 5, cc = flat & 31;
                float4 v = *(const float4*)&Af[(size_t)(m0 + r) * Kk + k0 + cc];
                half4 hv = { (f16)v.x, (f16)v.y, (f16)v.z, (f16)v.w };
                *(half4*)&Als[buf][r * 32 + cc] = hv;
            }
        } else {
            const f16* Af = (const f16*)Ag + (size_t)z * sA;
            #pragma unroll
            for (int c = 0; c < 2; ++c) {
                const int arow = w * 32 + c * 16;
                gl_lds16(Af + (size_t)(m0 + arow + srow) * Kk + k0 + scol,
                         &Als[buf][arow * 32]);
            }
        }
    };

    const int nk = Kk >> 5;
    stage(0, 0);
    int cur = 0;
    const int fr = lane & 15, fg = lane >> 4;

    for (int kt = 0; kt < nk; ++kt) {
        __syncthreads();
        if (kt + 1 < nk) stage(cur ^ 1, kt + 1);

        half8 a[4], b[4];
        #pragma unroll
        for (int i = 0; i < 4; ++i)
            a[i] = *(const half8*)&Als[cur][(wm * 64 + i * 16 + fr) * 32 + fg * 8];
        #pragma unroll
        for (int j = 0; j < 4; ++j)
            b[j] = *(const half8*)&Bls[cur][(wn * 64 + j * 16 + fr) * 32 + fg * 8];
        #pragma unroll
        for (int i = 0; i < 4; ++i)
            #pragma unroll
            for (int j = 0; j < 4; ++j)
                acc[i][j] = __builtin_amdgcn_mfma_f32_16x16x32_f16(a[i], b[j], acc[i][j], 0, 0, 0);
        cur ^= 1;
    }

    #pragma unroll
    for (int i = 0; i < 4; ++i) {
        const int gmb = m0 + wm * 64 + i * 16 + fg * 4;
        #pragma unroll
        for (int j = 0; j < 4; ++j) {
            const int gn = n0 + wn * 64 + j * 16 + fr;
            f32x4 v = acc[i][j];
            if (RELU) {
                v[0] = fmaxf(v[0], 0.f); v[1] = fmaxf(v[1], 0.f);
                v[2] = fmaxf(v[2], 0.f); v[3] = fmaxf(v[3], 0.f);
            }
            if constexpr (OMODE == 1) {
                f16* Ch = (f16*)Cg + (size_t)z * sC;
                #pragma unroll
                for (int r = 0; r < 4; ++r)
                    if (gmb + r < Mvalid) Ch[(size_t)(gmb + r) * Nn + gn] = (f16)v[r];
            } else {
                f16* Ct = (f16*)Cg + (size_t)z * sC;
                half4 hv = { (f16)v[0], (f16)v[1], (f16)v[2], (f16)v[3] };
                if (gmb + 3 < Mvalid) *(half4*)&Ct[(size_t)gn * ldct + gmb] = hv;
            }
        }
    }
}

// ---------------------------------------------------------------------------
// Fused recurrent step (r7 math: f32 Cb, bsum epilogue, fast_tanh).
// Grid (8, 40): each block computes TWO 128-row m-tiles -> 320 blocks = one
// full wave-of-blocks at 2/CU (no 120-block straggler wave; Whh L2-hot on
// the 2nd tile). h16 buffers are NP2 rows so staging reads stay in-bounds.
// ---------------------------------------------------------------------------
__global__ __launch_bounds__(256, 2)
void gemm_lstm(const f16* __restrict__ h16, const f16* __restrict__ Whh,
               const f16* __restrict__ U, const f16* __restrict__ V,
               const int* __restrict__ invt, const float* __restrict__ bsum,
               float* __restrict__ Cb, f16* __restrict__ h16_out,
               float* __restrict__ hout)
{
    __shared__ f16 Als[2][128 * 32];
    __shared__ f16 Bls[2][128 * 32];

    const int tid  = threadIdx.x;
    const int lane = tid & 63;
    const int w    = tid >> 6;
    const int wm   = w >> 1, wn = w & 1;
    const int n0   = blockIdx.x * 128;
    const int srow = lane >> 2, scol = (lane & 3) * 8;
    const int fr   = lane & 15, fg = lane >> 4;

    const int u = ((n0 >> 6) + wn) * 16 + fr;
    const int colbase = n0 + wn * 64 + fr;
    const float b0 = bsum[colbase],      b1 = bsum[colbase + 16],
                b2 = bsum[colbase + 32], b3 = bsum[colbase + 48];
    auto sig = [](float x) { return 1.f / (1.f + __expf(-x)); };

    for (int mhalf = 0; mhalf < 2; ++mhalf) {
        const int m0 = (blockIdx.y * 2 + mhalf) * 128;

        f32x4 acc[4][4] = {};
        auto stage = [&](int buf, int kt) {
            const int k0 = kt * 32;
            #pragma unroll
            for (int c = 0; c < 2; ++c) {
                const int row = w * 32 + c * 16;
                gl_lds16(Whh + (size_t)(n0 + row + srow) * H + k0 + scol, &Bls[buf][row * 32]);
                gl_lds16(h16 + (size_t)(m0 + row + srow) * H + k0 + scol, &Als[buf][row * 32]);
            }
        };

        stage(0, 0);
        int cur = 0;
        for (int kt = 0; kt < H / 32; ++kt) {
            __syncthreads();
            if (kt + 1 < H / 32) stage(cur ^ 1, kt + 1);
            half8 a[4], b[4];
            #pragma unroll
            for (int i = 0; i < 4; ++i)
                a[i] = *(const half8*)&Als[cur][(wm * 64 + i * 16 + fr) * 32 + fg * 8];
            #pragma unroll
            for (int j = 0; j < 4; ++j)
                b[j] = *(const half8*)&Bls[cur][(wn * 64 + j * 16 + fr) * 32 + fg * 8];
            #pragma unroll
            for (int i = 0; i < 4; ++i)
                #pragma unroll
                for (int j = 0; j < 4; ++j)
                    acc[i][j] = __builtin_amdgcn_mfma_f32_16x16x32_f16(a[i], b[j], acc[i][j], 0, 0, 0);
            cur ^= 1;
        }

        #pragma unroll
        for (int i = 0; i < 4; ++i) {
            const int nodeb = m0 + wm * 64 + i * 16 + fg * 4;
            #pragma unroll
            for (int r = 0; r < 4; ++r) {
                const int node = nodeb + r;
                if (node >= N) continue;
                const int p = invt[node];
                const f16* xb = (p >= 0) ? V + (size_t)p * G4 : U + (size_t)node * G4;
                const float zi = acc[i][0][r] + (float)xb[colbase]      + b0;
                const float zf = acc[i][1][r] + (float)xb[colbase + 16] + b1;
                const float zg = acc[i][2][r] + (float)xb[colbase + 32] + b2;
                const float zo = acc[i][3][r] + (float)xb[colbase + 48] + b3;
                const size_t ci = (size_t)node * H + u;
                const float c = sig(zf) * Cb[ci] + sig(zi) * fast_tanh(zg);
                Cb[ci] = c;
                const float hv = sig(zo) * fast_tanh(c);
                h16_out[ci] = (f16)hv;
                if (hout) hout[ci] = hv;
            }
        }
        // Next mhalf's stage(0,0) writes buf0 while stragglers read buf1 -> no
        // hazard; its first __syncthreads drains the gl_lds before reads.
    }
}

// GT[t][f][p] = Y0h[mask[t][p]][f]
__global__ __launch_bounds__(256)
void gather_T(const f16* __restrict__ Y0h, const int* __restrict__ mask,
              f16* __restrict__ GT)
{
    __shared__ f16 tile[64][F + 8];
    const int t = blockIdx.y, p0 = blockIdx.x * 64;
    const int tid = threadIdx.x;
    const int pr = tid >> 2;
    const int fc = (tid & 3) * 8;

    const int row = mask[t * M + p0 + pr];
    const f16* src = Y0h + (size_t)row * F;
    #pragma unroll
    for (int it = 0; it < 8; ++it) {
        const int f = it * 32 + fc;
        *(half8*)&tile[pr][f] = *(const half8*)&src[f];
    }
    __syncthreads();

    f16* dst = GT + ((size_t)t * F + tid) * M + p0;
    #pragma unroll
    for (int pc = 0; pc < 64; pc += 8) {
        half8 v;
        #pragma unroll
        for (int r = 0; r < 8; ++r) v[r] = tile[pc + r][tid];
        *(half8*)&dst[pc] = v;
    }
}

__global__ void cvt_f16(const float* __restrict__ s, f16* __restrict__ d, long long n)
{
    long long base = ((long long)blockIdx.x * blockDim.x + threadIdx.x) * 4;
    if (base + 3 < n) {
        float4 v = *(const float4*)&s[base];
        half4 hv = { (f16)v.x, (f16)v.y, (f16)v.z, (f16)v.w };
        *(half4*)&d[base] = hv;
    } else {
        for (long long k = base; k < n; ++k) d[k] = (f16)s[k];
    }
}

// ---------------------------------------------------------------------------
// Merged prologue prep: one launch replaces 7 tiny kernels.
// blocks [0,256)    : w0T  (transpose-cvt w0)
// blocks [256,512)  : w1T  (transpose-cvt w1)
// blocks [512,768)  : Wih perm-cvt (4 pcols/block)
// blocks [768,1024) : Whh perm-cvt
// block  1024       : bias_perm
// blocks [1025,1153): build_inv scatter
// blocks [1153,3653): nf -> nf16 cvt (4 elems/thread, exact)
// ---------------------------------------------------------------------------
__global__ __launch_bounds__(256)
void prep(const float* __restrict__ nf,   f16* __restrict__ nf16,
          const float* __restrict__ w0,   f16* __restrict__ w0T,
          const float* __restrict__ w1,   f16* __restrict__ w1T,
          const float* __restrict__ W_ih, f16* __restrict__ Wih16,
          const float* __restrict__ W_hh, f16* __restrict__ Whh16,
          const float* __restrict__ b_ih, const float* __restrict__ b_hh,
          float* __restrict__ bsum,
          const int* __restrict__ mask, int* __restrict__ inv)
{
    const int b = blockIdx.x, tid = threadIdx.x;
    if (b < 512) {                       // transpose-cvt w0 / w1
        const float* s = (b < 256) ? w0 : w1;
        f16* d = (b < 256) ? w0T : w1T;
        const int i = (b & 255) * 256 + tid;
        const int r = i % F, c = i / F;
        d[(size_t)c * F + r] = (f16)s[(size_t)r * F + c];
    } else if (b < 1024) {               // perm-cvt Wih / Whh
        const float* s = (b < 768) ? W_ih : W_hh;
        f16* d = (b < 768) ? Wih16 : Whh16;
        const int pcol = ((b < 768) ? (b - 512) : (b - 768)) * 4 + (tid >> 6);
        const int c64 = pcol >> 6, within = pcol & 63, gate = within >> 4, r = within & 15;
        const int srow = gate * 256 + c64 * 16 + r;
        const int k = (tid & 63) * 4;
        float4 v = *(const float4*)&s[(size_t)srow * F + k];
        half4 hv = { (f16)v.x, (f16)v.y, (f16)v.z, (f16)v.w };
        *(half4*)&d[(size_t)pcol * F + k] = hv;
    } else if (b == 1024) {              // bias_perm
        #pragma unroll
        for (int it = 0; it < 4; ++it) {
            const int pcol = it * 256 + tid;
            const int c64 = pcol >> 6, within = pcol & 63, gate = within >> 4, r = within & 15;
            const int srow = gate * 256 + c64 * 16 + r;
            bsum[pcol] = b_ih[srow] + b_hh[srow];
        }
    } else if (b < 1153) {               // build_inv
        const int i = (b - 1025) * 256 + tid;
        if (i < T * M) inv[(size_t)(i / M) * N + mask[i]] = i % M;
    } else {                             // nf -> nf16 (2500 blocks, exact fit)
        const long long base = ((long long)(b - 1153) * 256 + tid) * 4;
        float4 v = *(const float4*)&nf[base];
        half4 hv = { (f16)v.x, (f16)v.y, (f16)v.z, (f16)v.w };
        *(half4*)&nf16[base] = hv;
    }
}

extern "C" void kernel_launch(void* const* d_in, const int* in_sizes, int n_in,
                              void* d_out, int out_size, void* d_ws, size_t ws_size,
                              hipStream_t stream)
{
    const float* A_all = (const float*)d_in[0];
    const float* nf    = (const float*)d_in[1];
    const int*   mask  = (const int*)  d_in[2];
    const float* w0    = (const float*)d_in[3];
    const float* w1    = (const float*)d_in[4];
    const float* W_ih  = (const float*)d_in[5];
    const float* W_hh  = (const float*)d_in[6];
    const float* b_ih  = (const float*)d_in[7];
    const float* b_hh  = (const float*)d_in[8];
    float* h = (float*)d_out;

    char* wp = (char*)d_ws;
    auto alloc = [&](size_t bytes) { char* p = wp; wp += (bytes + 255) & ~(size_t)255; return p; };
    f16*   nf16  = (f16*)alloc((size_t)NP * F * 2);
    f16*   w0T   = (f16*)alloc((size_t)F * F * 2);
    f16*   w1T   = (f16*)alloc((size_t)F * F * 2);
    f16*   Wih16 = (f16*)alloc((size_t)G4 * F * 2);   // permuted rows
    f16*   Whh16 = (f16*)alloc((size_t)G4 * H * 2);   // permuted rows
    float* bsum  = (float*)alloc((size_t)G4 * 4);
    f16*   Y0h   = (f16*)alloc((size_t)NP * F * 2);
    f16*   Y1h   = (f16*)alloc((size_t)NP * F * 2);
    f16*   Uh    = (f16*)alloc((size_t)NP2 * G4 * 2); // permuted cols (NP2 rows)
    f16*   GT    = (f16*)alloc((size_t)T * F * M * 2);
    f16*   Z1b   = (f16*)alloc((size_t)T * M * F * 2);
    f16*   Z2T   = (f16*)alloc((size_t)T * F * M * 2);
    f16*   Z3b   = (f16*)alloc((size_t)T * M * F * 2);
    f16*   Vb    = (f16*)alloc((size_t)4 * M * G4 * 2);   // 4-step chunks
    float* Cb    = (float*)alloc((size_t)N * H * 4);      // f32 cell state
    f16*   h16   = (f16*)alloc((size_t)NP2 * H * 2);      // NP2 rows (chain pads)
    int*   inv   = (int*)alloc((size_t)T * N * 4);

    const size_t a16_bytes = (size_t)T * M * M * 2;
    const size_t used      = (size_t)(wp - (char*)d_ws);
    const bool   useA16    = (used + a16_bytes) <= ws_size;
    f16* A16 = useA16 ? (f16*)alloc(a16_bytes) : nullptr;

    hipMemsetAsync(Cb,  0,    (size_t)N * H * 4,    stream);
    hipMemsetAsync(h16, 0,    (size_t)NP2 * H * 2,  stream);
    hipMemsetAsync(nf16,0,    (size_t)NP * F * 2,   stream);
    hipMemsetAsync(inv, 0xFF, (size_t)T * N * 4,    stream);

    prep<<<3653, 256, 0, stream>>>(nf, nf16, w0, w0T, w1, w1T,
                                   W_ih, Wih16, W_hh, Whh16,
                                   b_ih, b_hh, bsum, mask, inv);

    gemm16<false,false,1><<<dim3(F / 128,  NP / 128, 1), 256, 0, stream>>>(nf16, 0, w0T,   0, Y0h, 0, F, F,  NP, 0);
    gemm16<false,false,1><<<dim3(F / 128,  NP / 128, 1), 256, 0, stream>>>(Y0h,  0, w1T,   0, Y1h, 0, F, F,  NP, 0);
    gemm16<false,false,1><<<dim3(G4 / 128, NP / 128, 1), 256, 0, stream>>>(Y1h,  0, Wih16, 0, Uh,  0, F, G4, NP, 0);

    gather_T<<<dim3(M / 64, T), 256, 0, stream>>>(Y0h, mask, GT);

    const long long sAmm = (long long)M * M;
    const long long sFM  = (long long)F * M;
    const long long sMF  = (long long)M * F;

    if (useA16) {
        // one-time fp32->f16 of A (134 MB, L3-resident for both passes)
        cvt_f16<<<(int)(((long long)T * M * M / 4 + 255) / 256), 256, 0, stream>>>(
            A_all, A16, (long long)T * M * M);
        gemm16<false,true, 1><<<dim3(2, 16, T), 256, 0, stream>>>(A16, sAmm, GT,  sFM, Z1b, sMF, M, F, M, 0);
        gemm16<false,false,2><<<dim3(2, 16, T), 256, 0, stream>>>(Z1b, sMF,  w1T, 0,   Z2T, sFM, F, F, M, M);
        gemm16<false,true, 1><<<dim3(2, 16, T), 256, 0, stream>>>(A16, sAmm, Z2T, sFM, Z3b, sMF, M, F, M, 0);
    } else {
        gemm16<true, true, 1><<<dim3(2, 16, T), 256, 0, stream>>>(A_all, sAmm, GT,  sFM, Z1b, sMF, M, F, M, 0);
        gemm16<false,false,2><<<dim3(2, 16, T), 256, 0, stream>>>(Z1b,  sMF,  w1T, 0,   Z2T, sFM, F, F, M, M);
        gemm16<true, true, 1><<<dim3(2, 16, T), 256, 0, stream>>>(A_all, sAmm, Z2T, sFM, Z3b, sMF, M, F, M, 0);
    }

    for (int t = 0; t < T; ++t) {
        if ((t & 3) == 0) {  // V[t..t+3] = Z3 @ W_ih^T (4-step batch, r7 shape)
            gemm16<false,false,1><<<dim3(G4 / 128, M / 128, 4), 256, 0, stream>>>(
                Z3b + (size_t)t * M * F, sMF, Wih16, 0, Vb, (long long)M * G4, F, G4, M, 0);
        }
        gemm_lstm<<<dim3(G4 / 128, NP2 / 256, 1), 256, 0, stream>>>(
            h16, Whh16, Uh, Vb + (size_t)(t & 3) * M * G4, inv + (size_t)t * N,
            bsum, Cb, h16, (t == T - 1) ? h : nullptr);
    }
}

// Round 12
// 748.049 us; speedup vs baseline: 1.3068x; 1.3068x over previous
//
#include <hip/hip_runtime.h>
#include <cstdint>
#include <cstddef>

#pragma clang diagnostic ignored "-Waddress-space-conversion"

constexpr int T  = 16;
constexpr int N  = 10000;
constexpr int M  = 2048;
constexpr int F  = 256;
constexpr int H  = 256;
constexpr int G4 = 1024;
constexpr int NP = 10112;   // N padded to multiple of 128

typedef _Float16 f16;
using half8  = __attribute__((ext_vector_type(8))) f16;
using half4  = __attribute__((ext_vector_type(4))) f16;
using f32x4  = __attribute__((ext_vector_type(4))) float;

typedef __attribute__((address_space(1))) const void gas_t;
typedef __attribute__((address_space(3))) void las_t;

__device__ __forceinline__ void gl_lds16(const f16* g, f16* l) {
    __builtin_amdgcn_global_load_lds((gas_t*)g, (las_t*)l, 16, 0, 0);
}

__device__ __forceinline__ float fast_tanh(float x) {
    const float ax = fabsf(x);
    const float e  = __expf(-2.f * ax);
    const float t  = (1.f - e) / (1.f + e);
    return copysignf(t, x);
}

// ---------------------------------------------------------------------------
// Generic MFMA GEMM (round-7 structure, unchanged).
// r8 lesson: no global stores inside the staged K-loop (vmcnt drain).
// r10 lesson: grid.sync() persistent chain = 116 us/step; dead end.
// r11 lesson: multi-tile-per-block chain grids worsen CU load balance.
// ---------------------------------------------------------------------------
template<bool AF32, bool RELU, int OMODE>
__global__ __launch_bounds__(256, 2)
void gemm16(const void* __restrict__ Ag, long long sA,
            const f16*  __restrict__ Bg, long long sB,
            void*       __restrict__ Cg, long long sC,
            int Kk, int Nn, int Mvalid, int ldct)
{
    __shared__ f16 Als[2][128 * 32];
    __shared__ f16 Bls[2][128 * 32];

    const int tid  = threadIdx.x;
    const int lane = tid & 63;
    const int w    = tid >> 6;
    const int wm   = w >> 1, wn = w & 1;
    const int m0   = blockIdx.y * 128, n0 = blockIdx.x * 128;
    const int z    = blockIdx.z;

    const f16* Bt = Bg + (size_t)z * sB;
    const int srow = lane >> 2;
    const int scol = (lane & 3) * 8;

    f32x4 acc[4][4] = {};

    auto stage = [&](int buf, int kt) {
        const int k0 = kt * 32;
        #pragma unroll
        for (int c = 0; c < 2; ++c) {
            const int brow = w * 32 + c * 16;
            gl_lds16(Bt + (size_t)(n0 + brow + srow) * Kk + k0 + scol,
                     &Bls[buf][brow * 32]);
        }
        if constexpr (AF32) {
            const float* Af = (const float*)Ag + (size_t)z * sA;
            #pragma unroll
            for (int p = 0; p < 4; ++p) {
                const int flat = p * 1024 + tid * 4;
                const int r = flat >> 5, cc = flat & 31;
                float4 v = *(const float4*)&Af[(size_t)(m0 + r) * Kk + k0 + cc];
                half4 hv = { (f16)v.x, (f16)v.y, (f16)v.z, (f16)v.w };
                *(half4*)&Als[buf][r * 32 + cc] = hv;
            }
        } else {
            const f16* Af = (const f16*)Ag + (size_t)z * sA;
            #pragma unroll
            for (int c = 0; c < 2; ++c) {
                const int arow = w * 32 + c * 16;
                gl_lds16(Af + (size_t)(m0 + arow + srow) * Kk + k0 + scol,
                         &Als[buf][arow * 32]);
            }
        }
    };

    const int nk = Kk >> 5;
    stage(0, 0);
    int cur = 0;
    const int fr = lane & 15, fg = lane >> 4;

    for (int kt = 0; kt < nk; ++kt) {
        __syncthreads();
        if (kt + 1 < nk) stage(cur ^ 1, kt + 1);

        half8 a[4], b[4];
        #pragma unroll
        for (int i = 0; i < 4; ++i)
            a[i] = *(const half8*)&Als[cur][(wm * 64 + i * 16 + fr) * 32 + fg * 8];
        #pragma unroll
        for (int j = 0; j < 4; ++j)
            b[j] = *(const half8*)&Bls[cur][(wn * 64 + j * 16 + fr) * 32 + fg * 8];
        #pragma unroll
        for (int i = 0; i < 4; ++i)
            #pragma unroll
            for (int j = 0; j < 4; ++j)
                acc[i][j] = __builtin_amdgcn_mfma_f32_16x16x32_f16(a[i], b[j], acc[i][j], 0, 0, 0);
        cur ^= 1;
    }

    #pragma unroll
    for (int i = 0; i < 4; ++i) {
        const int gmb = m0 + wm * 64 + i * 16 + fg * 4;
        #pragma unroll
        for (int j = 0; j < 4; ++j) {
            const int gn = n0 + wn * 64 + j * 16 + fr;
            f32x4 v = acc[i][j];
            if (RELU) {
                v[0] = fmaxf(v[0], 0.f); v[1] = fmaxf(v[1], 0.f);
                v[2] = fmaxf(v[2], 0.f); v[3] = fmaxf(v[3], 0.f);
            }
            if constexpr (OMODE == 1) {
                f16* Ch = (f16*)Cg + (size_t)z * sC;
                #pragma unroll
                for (int r = 0; r < 4; ++r)
                    if (gmb + r < Mvalid) Ch[(size_t)(gmb + r) * Nn + gn] = (f16)v[r];
            } else {
                f16* Ct = (f16*)Cg + (size_t)z * sC;
                half4 hv = { (f16)v[0], (f16)v[1], (f16)v[2], (f16)v[3] };
                if (gmb + 3 < Mvalid) *(half4*)&Ct[(size_t)gn * ldct + gmb] = hv;
            }
        }
    }
}

// ---------------------------------------------------------------------------
// Fused recurrent step (round-7 verbatim: f32 Cb, bsum epilogue, fast_tanh,
// grid (8, 79), launch_bounds (256,2)).
// ---------------------------------------------------------------------------
__global__ __launch_bounds__(256, 2)
void gemm_lstm(const f16* __restrict__ h16, const f16* __restrict__ Whh,
               const f16* __restrict__ U, const f16* __restrict__ V,
               const int* __restrict__ invt, const float* __restrict__ bsum,
               float* __restrict__ Cb, f16* __restrict__ h16_out,
               float* __restrict__ hout)
{
    __shared__ f16 Als[2][128 * 32];
    __shared__ f16 Bls[2][128 * 32];

    const int tid  = threadIdx.x;
    const int lane = tid & 63;
    const int w    = tid >> 6;
    const int wm   = w >> 1, wn = w & 1;
    const int m0   = blockIdx.y * 128, n0 = blockIdx.x * 128;

    const int srow = lane >> 2;
    const int scol = (lane & 3) * 8;

    f32x4 acc[4][4] = {};

    auto stage = [&](int buf, int kt) {
        const int k0 = kt * 32;
        #pragma unroll
        for (int c = 0; c < 2; ++c) {
            const int row = w * 32 + c * 16;
            gl_lds16(Whh + (size_t)(n0 + row + srow) * H + k0 + scol, &Bls[buf][row * 32]);
            gl_lds16(h16 + (size_t)(m0 + row + srow) * H + k0 + scol, &Als[buf][row * 32]);
        }
    };

    stage(0, 0);
    int cur = 0;
    const int fr = lane & 15, fg = lane >> 4;

    for (int kt = 0; kt < H / 32; ++kt) {
        __syncthreads();
        if (kt + 1 < H / 32) stage(cur ^ 1, kt + 1);
        half8 a[4], b[4];
        #pragma unroll
        for (int i = 0; i < 4; ++i)
            a[i] = *(const half8*)&Als[cur][(wm * 64 + i * 16 + fr) * 32 + fg * 8];
        #pragma unroll
        for (int j = 0; j < 4; ++j)
            b[j] = *(const half8*)&Bls[cur][(wn * 64 + j * 16 + fr) * 32 + fg * 8];
        #pragma unroll
        for (int i = 0; i < 4; ++i)
            #pragma unroll
            for (int j = 0; j < 4; ++j)
                acc[i][j] = __builtin_amdgcn_mfma_f32_16x16x32_f16(a[i], b[j], acc[i][j], 0, 0, 0);
        cur ^= 1;
    }

    const int u = ((n0 >> 6) + wn) * 16 + fr;
    const int colbase = n0 + wn * 64 + fr;
    const float b0 = bsum[colbase],      b1 = bsum[colbase + 16],
                b2 = bsum[colbase + 32], b3 = bsum[colbase + 48];
    auto sig = [](float x) { return 1.f / (1.f + __expf(-x)); };

    #pragma unroll
    for (int i = 0; i < 4; ++i) {
        const int nodeb = m0 + wm * 64 + i * 16 + fg * 4;
        #pragma unroll
        for (int r = 0; r < 4; ++r) {
            const int node = nodeb + r;
            if (node >= N) continue;
            const int p = invt[node];
            const f16* xb = (p >= 0) ? V + (size_t)p * G4 : U + (size_t)node * G4;
            const float zi = acc[i][0][r] + (float)xb[colbase]      + b0;
            const float zf = acc[i][1][r] + (float)xb[colbase + 16] + b1;
            const float zg = acc[i][2][r] + (float)xb[colbase + 32] + b2;
            const float zo = acc[i][3][r] + (float)xb[colbase + 48] + b3;
            const size_t ci = (size_t)node * H + u;
            const float c = sig(zf) * Cb[ci] + sig(zi) * fast_tanh(zg);
            Cb[ci] = c;
            const float hv = sig(zo) * fast_tanh(c);
            h16_out[ci] = (f16)hv;
            if (hout) hout[ci] = hv;
        }
    }
}

// GT[t][f][p] = Y0h[mask[t][p]][f]
__global__ __launch_bounds__(256)
void gather_T(const f16* __restrict__ Y0h, const int* __restrict__ mask,
              f16* __restrict__ GT)
{
    __shared__ f16 tile[64][F + 8];
    const int t = blockIdx.y, p0 = blockIdx.x * 64;
    const int tid = threadIdx.x;
    const int pr = tid >> 2;
    const int fc = (tid & 3) * 8;

    const int row = mask[t * M + p0 + pr];
    const f16* src = Y0h + (size_t)row * F;
    #pragma unroll
    for (int it = 0; it < 8; ++it) {
        const int f = it * 32 + fc;
        *(half8*)&tile[pr][f] = *(const half8*)&src[f];
    }
    __syncthreads();

    f16* dst = GT + ((size_t)t * F + tid) * M + p0;
    #pragma unroll
    for (int pc = 0; pc < 64; pc += 8) {
        half8 v;
        #pragma unroll
        for (int r = 0; r < 8; ++r) v[r] = tile[pc + r][tid];
        *(half8*)&dst[pc] = v;
    }
}

__global__ void cvt_f16(const float* __restrict__ s, f16* __restrict__ d, long long n)
{
    long long base = ((long long)blockIdx.x * blockDim.x + threadIdx.x) * 4;
    if (base + 3 < n) {
        float4 v = *(const float4*)&s[base];
        half4 hv = { (f16)v.x, (f16)v.y, (f16)v.z, (f16)v.w };
        *(half4*)&d[base] = hv;
    } else {
        for (long long k = base; k < n; ++k) d[k] = (f16)s[k];
    }
}

// ---------------------------------------------------------------------------
// Merged prologue: one launch replaces 7 prep kernels + 3 memsets.
// All ranges exact-fit (no guards needed):
//  [0,256)      w0T transpose-cvt        (65536 elems)
//  [256,512)    w1T transpose-cvt
//  [512,768)    Wih perm-cvt (4 pcols/block)
//  [768,1024)   Whh perm-cvt
//  1024         bias_perm (1024 pcols)
//  [1025,1153)  build_inv scatter (T*M = 32768 = 128*256; inv pre-filled -1
//               by the hipMemsetAsync enqueued BEFORE this kernel)
//  [1153,3653)  nf->nf16 cvt (2500*256*4 = N*F exact)
//  [3653,3667)  nf16 pad rows [N,NP) zero (14*256 half8 = 3584 exact)
//  [3667,6167)  Cb zero f32 (2500*256 float4 = N*H exact)
//  [6167,7431)  h16 zero (1264*256 half8 = NP*H exact)
// ---------------------------------------------------------------------------
__global__ __launch_bounds__(256)
void prep(const float* __restrict__ nf,   f16* __restrict__ nf16,
          const float* __restrict__ w0,   f16* __restrict__ w0T,
          const float* __restrict__ w1,   f16* __restrict__ w1T,
          const float* __restrict__ W_ih, f16* __restrict__ Wih16,
          const float* __restrict__ W_hh, f16* __restrict__ Whh16,
          const float* __restrict__ b_ih, const float* __restrict__ b_hh,
          float* __restrict__ bsum,
          const int* __restrict__ mask, int* __restrict__ inv,
          float* __restrict__ Cb, f16* __restrict__ h16)
{
    const int b = blockIdx.x, tid = threadIdx.x;
    if (b < 512) {                        // transpose-cvt w0 / w1
        const float* s = (b < 256) ? w0 : w1;
        f16* d = (b < 256) ? w0T : w1T;
        const int i = (b & 255) * 256 + tid;
        const int r = i % F, c = i / F;
        d[(size_t)c * F + r] = (f16)s[(size_t)r * F + c];
    } else if (b < 1024) {                // perm-cvt Wih / Whh
        const float* s = (b < 768) ? W_ih : W_hh;
        f16* d = (b < 768) ? Wih16 : Whh16;
        const int pcol = ((b - 512) & 255) * 4 + (tid >> 6);
        const int c64 = pcol >> 6, within = pcol & 63, gate = within >> 4, r = within & 15;
        const int srow = gate * 256 + c64 * 16 + r;
        const int k = (tid & 63) * 4;
        float4 v = *(const float4*)&s[(size_t)srow * F + k];
        half4 hv = { (f16)v.x, (f16)v.y, (f16)v.z, (f16)v.w };
        *(half4*)&d[(size_t)pcol * F + k] = hv;
    } else if (b == 1024) {               // bias_perm
        #pragma unroll
        for (int it = 0; it < 4; ++it) {
            const int pcol = it * 256 + tid;
            const int c64 = pcol >> 6, within = pcol & 63, gate = within >> 4, r = within & 15;
            const int srow = gate * 256 + c64 * 16 + r;
            bsum[pcol] = b_ih[srow] + b_hh[srow];
        }
    } else if (b < 1153) {                // build_inv scatter
        const int i = (b - 1025) * 256 + tid;
        inv[(size_t)(i / M) * N + mask[i]] = i % M;
    } else if (b < 3653) {                // nf -> nf16
        const long long base = ((long long)(b - 1153) * 256 + tid) * 4;
        float4 v = *(const float4*)&nf[base];
        half4 hv = { (f16)v.x, (f16)v.y, (f16)v.z, (f16)v.w };
        *(half4*)&nf16[base] = hv;
    } else if (b < 3667) {                // nf16 pad rows [N,NP) = 0
        const int idx = (b - 3653) * 256 + tid;
        half8 z = {};
        *(half8*)&nf16[(size_t)N * F + (size_t)idx * 8] = z;
    } else if (b < 6167) {                // Cb = 0
        const long long base = ((long long)(b - 3667) * 256 + tid) * 4;
        *(float4*)&Cb[base] = make_float4(0.f, 0.f, 0.f, 0.f);
    } else {                              // h16 = 0
        const long long idx = (long long)(b - 6167) * 256 + tid;
        half8 z = {};
        *(half8*)&h16[idx * 8] = z;
    }
}

extern "C" void kernel_launch(void* const* d_in, const int* in_sizes, int n_in,
                              void* d_out, int out_size, void* d_ws, size_t ws_size,
                              hipStream_t stream)
{
    const float* A_all = (const float*)d_in[0];
    const float* nf    = (const float*)d_in[1];
    const int*   mask  = (const int*)  d_in[2];
    const float* w0    = (const float*)d_in[3];
    const float* w1    = (const float*)d_in[4];
    const float* W_ih  = (const float*)d_in[5];
    const float* W_hh  = (const float*)d_in[6];
    const float* b_ih  = (const float*)d_in[7];
    const float* b_hh  = (const float*)d_in[8];
    float* h = (float*)d_out;

    char* wp = (char*)d_ws;
    auto alloc = [&](size_t bytes) { char* p = wp; wp += (bytes + 255) & ~(size_t)255; return p; };
    f16*   nf16  = (f16*)alloc((size_t)NP * F * 2);
    f16*   w0T   = (f16*)alloc((size_t)F * F * 2);
    f16*   w1T   = (f16*)alloc((size_t)F * F * 2);
    f16*   Wih16 = (f16*)alloc((size_t)G4 * F * 2);   // permuted rows
    f16*   Whh16 = (f16*)alloc((size_t)G4 * H * 2);   // permuted rows
    float* bsum  = (float*)alloc((size_t)G4 * 4);
    f16*   Y0h   = (f16*)alloc((size_t)NP * F * 2);
    f16*   Y1h   = (f16*)alloc((size_t)NP * F * 2);
    f16*   Uh    = (f16*)alloc((size_t)NP * G4 * 2);  // permuted cols
    f16*   GT    = (f16*)alloc((size_t)T * F * M * 2);
    f16*   Z1b   = (f16*)alloc((size_t)T * M * F * 2);
    f16*   Z2T   = (f16*)alloc((size_t)T * F * M * 2);
    f16*   Z3b   = (f16*)alloc((size_t)T * M * F * 2);
    f16*   Vb    = (f16*)alloc((size_t)4 * M * G4 * 2);   // 4-step chunks
    float* Cb    = (float*)alloc((size_t)N * H * 4);      // f32 cell state
    f16*   h16   = (f16*)alloc((size_t)NP * H * 2);
    int*   inv   = (int*)alloc((size_t)T * N * 4);

    // A16 is optional (needs +134 MB scratch); deterministic ws_size guard.
    const size_t a16_bytes = (size_t)T * M * M * 2;
    const size_t used      = (size_t)(wp - (char*)d_ws);
    const bool   useA16    = (used + a16_bytes) <= ws_size;
    f16* A16 = useA16 ? (f16*)alloc(a16_bytes) : nullptr;

    // inv must be -1-filled BEFORE prep's scatter range runs.
    hipMemsetAsync(inv, 0xFF, (size_t)T * N * 4, stream);

    prep<<<7431, 256, 0, stream>>>(nf, nf16, w0, w0T, w1, w1T,
                                   W_ih, Wih16, W_hh, Whh16,
                                   b_ih, b_hh, bsum, mask, inv, Cb, h16);

    gemm16<false,false,1><<<dim3(F / 128,  NP / 128, 1), 256, 0, stream>>>(nf16, 0, w0T,   0, Y0h, 0, F, F,  NP, 0);
    gemm16<false,false,1><<<dim3(F / 128,  NP / 128, 1), 256, 0, stream>>>(Y0h,  0, w1T,   0, Y1h, 0, F, F,  NP, 0);
    gemm16<false,false,1><<<dim3(G4 / 128, NP / 128, 1), 256, 0, stream>>>(Y1h,  0, Wih16, 0, Uh,  0, F, G4, NP, 0);

    gather_T<<<dim3(M / 64, T), 256, 0, stream>>>(Y0h, mask, GT);

    const long long sAmm = (long long)M * M;
    const long long sFM  = (long long)F * M;
    const long long sMF  = (long long)M * F;

    if (useA16) {
        // one-time fp32->f16 of A (134 MB, L3-resident for both passes)
        cvt_f16<<<(int)(((long long)T * M * M / 4 + 255) / 256), 256, 0, stream>>>(
            A_all, A16, (long long)T * M * M);
        gemm16<false,true, 1><<<dim3(2, 16, T), 256, 0, stream>>>(A16, sAmm, GT,  sFM, Z1b, sMF, M, F, M, 0);
        gemm16<false,false,2><<<dim3(2, 16, T), 256, 0, stream>>>(Z1b, sMF,  w1T, 0,   Z2T, sFM, F, F, M, M);
        gemm16<false,true, 1><<<dim3(2, 16, T), 256, 0, stream>>>(A16, sAmm, Z2T, sFM, Z3b, sMF, M, F, M, 0);
    } else {
        gemm16<true, true, 1><<<dim3(2, 16, T), 256, 0, stream>>>(A_all, sAmm, GT,  sFM, Z1b, sMF, M, F, M, 0);
        gemm16<false,false,2><<<dim3(2, 16, T), 256, 0, stream>>>(Z1b,  sMF,  w1T, 0,   Z2T, sFM, F, F, M, M);
        gemm16<true, true, 1><<<dim3(2, 16, T), 256, 0, stream>>>(A_all, sAmm, Z2T, sFM, Z3b, sMF, M, F, M, 0);
    }

    for (int t = 0; t < T; ++t) {
        if ((t & 3) == 0) {  // V[t..t+3] = Z3 @ W_ih^T (4-step batch, r7 shape)
            gemm16<false,false,1><<<dim3(G4 / 128, M / 128, 4), 256, 0, stream>>>(
                Z3b + (size_t)t * M * F, sMF, Wih16, 0, Vb, (long long)M * G4, F, G4, M, 0);
        }
        gemm_lstm<<<dim3(G4 / 128, NP / 128, 1), 256, 0, stream>>>(
            h16, Whh16, Uh, Vb + (size_t)(t & 3) * M * G4, inv + (size_t)t * N,
            bsum, Cb, h16, (t == T - 1) ? h : nullptr);
    }
}